// Round 12
// baseline (159.246 us; speedup 1.0000x reference)
//
#include <hip/hip_runtime.h>

// FullScan via bf16 MFMA 32x32x16, full-M packing.
// out[k,t] = sum_{d<16,w<64} x[d,t+w]*P[k,d,w], K=8, L=1e6.
// M=32 rows = (k, tap-group g): row m = k + 8g (g covers taps [16g,16g+16)).
//   D_g[k](s) = sum_{c<16,d} P[k,d,16g+c] x[d,s+c]
//   out[k,t]  = sum_g D_g[k](t + 16g)
// C/D: col=lane&31, row=(reg&3)+8*(reg>>2)+4h => reg kk+4g = D_g[kk+4h](n).
// R16 = R15 with the compile fix: __builtin_amdgcn_global_load_lds needs a
//   LITERAL offset arg -> fold the 16B/inst advance into the global pointer
//   (gp + j*4 floats), offset immediate 0. Design unchanged:
//   STAGING VIA global_load_lds (fp32, zero-VGPR, deep MLP).
//   Diagnosis: 8 nulls; quantitative fit is fetch-latency*MLP:
//   128B in flight/wave * 12 waves/CU * 256 CU / 700cy = 1.3 TB/s ==
//   measured 1.2 TB/s; 68MB / 1.3TB/s == the 52-55us wall.
//   Fix: 37 back-to-back global_load_lds dword per wave (9.5KB in flight,
//   one vmcnt drain at the barrier). LDS holds fp32, linear dest =
//   wave-uniform base + lane*4B; SOURCE swizzle (m173) makes linear LDS
//   the bank-swizzled layout; B-read XORs the 16B-unit with (pos&3).
//   bf16 conversion at B-read uses the SAME f2bf bit trick ->
//   bit-identical numerics. fp32 LDS forces OTW=4 (XS=592, 37.9KB).
//   Compute/epilogue = R10 verbatim.

constexpr int D    = 16;
constexpr int L    = 1000000;
constexpr int W    = 64;
constexpr int K    = 8;
constexpr int PADL = 31;
constexpr int NMID = L - W + 1;          // 999937
constexpr int TPB  = 256;                // 4 waves
constexpr int OTW  = 4;                  // out 32-pos tiles per wave
constexpr int CTW  = OTW + 2;            // computed tiles per wave
constexpr int BLK_OUT = 4 * OTW * 32;    // 512 positions per block
constexpr int XS   = 592;                // staged positions (need 591)
constexpr int SROWS = XS / 4;            // 148 4-row groups
constexpr int SPW  = SROWS / 4;          // 37 global_load_lds per wave
constexpr int NBLK = (NMID + BLK_OUT - 1) / BLK_OUT;   // 1954
constexpr int NGRID = NBLK + K;          // +8 edge blocks

typedef __attribute__((ext_vector_type(8)))  short short8;
typedef __attribute__((ext_vector_type(16))) float floatx16;

__device__ __forceinline__ unsigned short f2bf(float f) {
    union { float f; unsigned u; } v; v.f = f;
    unsigned u = v.u + 0x7fff + ((v.u >> 16) & 1);   // RNE
    return (unsigned short)(u >> 16);
}

__global__ __launch_bounds__(TPB, 3) void fullscan_mid(
    const float* __restrict__ x, const float* __restrict__ P,
    const unsigned short* __restrict__ afr, float* __restrict__ out)
{
    // fp32 staged x, source-swizzled: word Wd=(r*16+w) holds
    // x[d = 4*((w>>2)^(r&3)) + (w&3)][s0 + r].
    __shared__ __align__(16) float xs32[XS * 16];   // 37888 B
    const int bid = blockIdx.x;
    const int tid = threadIdx.x;

    if (bid >= NBLK) {
        // Edge block: k = bid - NBLK, 63 outputs (fp32 exact).
        const int k = bid - NBLK;
        const int j = tid;
        if (j < PADL) {
            float acc = 0.0f;
            for (int m = 0; m <= 32 + j; ++m)
#pragma unroll
                for (int d = 0; d < D; ++d)
                    acc = fmaf(x[d * L + m], P[(k * D + d) * W + m], acc);
            out[k * L + j] = acc;
        } else if (j < 2 * PADL + 1) {
            const int jj = j - PADL;                  // 0..31
            float acc = 0.0f;
            for (int m = jj + 1; m < W; ++m)
#pragma unroll
                for (int d = 0; d < D; ++d)
                    acc = fmaf(x[d * L + (L - W) + m], P[(k * D + d) * W + m], acc);
            out[k * L + PADL + NMID + jj] = acc;
        }
        return;
    }

    const int s0   = bid * BLK_OUT;
    const int lane = tid & 63;
    const int wv   = tid >> 6;

    // ---- Staging: global_load_lds fp32, 37 insts/wave back-to-back ----
    // Lane l of inst (wv,j) stages LDS word (wv*SPW+j)*64 + l, i.e.
    // row r=(wv*SPW+j)*4 + (l>>4), word w=l&15. Source swizzle: word must
    // hold d = 4*((w>>2)^(r&3)) + (w&3); r&3 == l>>4 (rows per inst are
    // 4-aligned), so d is lane-constant. Global addr advances 4 floats
    // (16B) per inst — folded into the pointer (offset arg must be
    // a literal; j*16 failed to compile in R15).
    {
        const int rof = lane >> 4;                       // 0..3 == r&3
        const int dsw = 4 * (((lane >> 2) & 3) ^ rof) + (lane & 3);
        if (s0 + XS <= L) {
            typedef const __attribute__((address_space(1))) float gfloat;
            typedef __attribute__((address_space(3))) float lfloat;
            gfloat* gp = (gfloat*)(x + (size_t)dsw * L + s0 + rof
                                     + (size_t)wv * (SPW * 4));
            lfloat* lp = (lfloat*)(xs32 + wv * (SPW * 64));
#pragma unroll
            for (int j = 0; j < SPW; ++j)
                __builtin_amdgcn_global_load_lds(gp + j * 4, lp + j * 64, 4, 0, 0);
        } else {
            // Last mid block only: scalar fallback, same swizzled layout.
#pragma unroll 1
            for (int i = 0; i < (XS * 16) / TPB; ++i) {   // 37 iters
                const int Wd = i * TPB + tid;
                const int r  = Wd >> 4, w = Wd & 15;
                const int d  = 4 * ((w >> 2) ^ (r & 3)) + (w & 3);
                const int pos = s0 + r;
                xs32[Wd] = (pos < L) ? x[(size_t)d * L + pos] : 0.0f;
            }
        }
    }

    // Resident A fragments (bf16 from prep table; queue behind staging).
    short8 A[16];
#pragma unroll
    for (int c = 0; c < 16; ++c)
        A[c] = *(const short8*)(afr + (c * 64 + lane) * 8);

    __syncthreads();   // drains the global_load_lds queue (vmcnt 0)

    const int n  = lane & 31;
    const int h  = lane >> 5;
    const int wbase = wv * OTW;

    // B-frag read: d-range [8h,8h+8) at row pos lives in 16B units
    // u0=(2h)^(pos&3), u1=(2h+1)^(pos&3) (float4 each, d ascending).
    // Convert with the SAME f2bf as before -> bit-identical results.
#define LD_LO(pos) (*(const float4*)&xs32[(pos) * 16 + ((((2 * h)) ^ ((pos) & 3)) << 2)])
#define LD_HI(pos) (*(const float4*)&xs32[(pos) * 16 + ((((2 * h + 1)) ^ ((pos) & 3)) << 2)])

    float pendA[4], pendB[4], prev4[4], prev12[4];

#pragma unroll
    for (int jj = 0; jj < CTW; ++jj) {
        floatx16 acc;
#pragma unroll
        for (int r = 0; r < 16; ++r) acc[r] = 0.0f;
        const int p0 = (wbase + jj) * 32 + n;

        float4 lo = LD_LO(p0), hi = LD_HI(p0);
#pragma unroll
        for (int c = 0; c < 16; ++c) {
            float4 lo_n, hi_n;
            if (c < 15) { lo_n = LD_LO(p0 + c + 1); hi_n = LD_HI(p0 + c + 1); }
            short8 B;
            B[0] = (short)f2bf(lo.x); B[1] = (short)f2bf(lo.y);
            B[2] = (short)f2bf(lo.z); B[3] = (short)f2bf(lo.w);
            B[4] = (short)f2bf(hi.x); B[5] = (short)f2bf(hi.y);
            B[6] = (short)f2bf(hi.z); B[7] = (short)f2bf(hi.w);
            acc = __builtin_amdgcn_mfma_f32_32x32x16_bf16(A[c], B, acc, 0, 0, 0);
            lo = lo_n; hi = hi_n;
        }

        if (jj >= 2) {
            const int ot = jj - 2;
            const int t = s0 + (wbase + ot) * 32 + n;
#pragma unroll
            for (int kk = 0; kk < 4; ++kk) {
                const float g3t = (n >= 16) ? prev12[kk] : acc[kk + 12];
                const float v = pendA[kk] + __shfl_xor(g3t, 16, 64);
                if (t < NMID)
                    out[(kk + 4 * h) * L + PADL + t] = v;
            }
        }
        if (jj >= 1) {
#pragma unroll
            for (int kk = 0; kk < 4; ++kk) {
                const float g1t = (n >= 16) ? prev4[kk] : acc[kk + 4];
                pendA[kk] = pendB[kk] + acc[kk + 8] + __shfl_xor(g1t, 16, 64);
            }
        }
#pragma unroll
        for (int kk = 0; kk < 4; ++kk) {
            pendB[kk]  = acc[kk];
            prev4[kk]  = acc[kk + 4];
            prev12[kk] = acc[kk + 12];
        }
    }
#undef LD_LO
#undef LD_HI
}

// Prep: A-fragment table. afr[c][lane][j] = bf16(P[k, d, w]),
// m=lane&31, h=lane>>5, k=m&7, g=m>>3, d=8h+j, w=16g+c.
__global__ void fullscan_prep(const float* __restrict__ P,
                              unsigned short* __restrict__ afr)
{
    const int u = blockIdx.x * 256 + threadIdx.x;   // 32 blocks x 256 = 8192
    const int c = u >> 9, lane = (u >> 3) & 63, j = u & 7;
    const int m = lane & 31, h = lane >> 5;
    const int k = m & 7, g = m >> 3;
    const int d = 8 * h + j;
    const int w = 16 * g + c;
    afr[u] = f2bf(P[(k * D + d) * W + w]);
}

extern "C" void kernel_launch(void* const* d_in, const int* in_sizes, int n_in,
                              void* d_out, int out_size, void* d_ws, size_t ws_size,
                              hipStream_t stream)
{
    const float* x = (const float*)d_in[0];   // (D, L)
    const float* P = (const float*)d_in[1];   // (K, D, W)
    float* out = (float*)d_out;
    unsigned short* afr = (unsigned short*)d_ws;   // 16 KB

    hipLaunchKernelGGL(fullscan_prep, dim3(32), dim3(256), 0, stream, P, afr);
    hipLaunchKernelGGL(fullscan_mid, dim3(NGRID), dim3(TPB), 0, stream,
                       x, P, afr, out);
}

// Round 13
// 138.123 us; speedup vs baseline: 1.1529x; 1.1529x over previous
//
#include <hip/hip_runtime.h>

// FullScan via bf16 MFMA 32x32x16, full-M packing.
// out[k,t] = sum_{d<16,w<64} x[d,t+w]*P[k,d,w], K=8, L=1e6.
// M=32 rows = (k, tap-group g): row m = k + 8g (g covers taps [16g,16g+16)).
//   D_g[k](s) = sum_{c<16,d} P[k,d,16g+c] x[d,s+c]
//   out[k,t]  = sum_g D_g[k](t + 16g)
// C/D: col=lane&31, row=(reg&3)+8*(reg>>2)+4h => reg kk+4g = D_g[kk+4h](n).
// R17: conflict-free staging writes + prep fusion, on the R11 base.
//   R16 lesson: conflicts<->time slope ~2us/M (18M cost +30us). Bank-start
//   enumeration: R8's layout u16 = h ^ ((pos>>2)&1) already has PERFECT
//   2-way-free reads (starts cover all 8 slots / 8 lanes); R9's row-XOR
//   degraded reads (why it was null). R8's 4.37M conflicts were all
//   write-side (pos&3=j fixed per inst, rows 128B-aligned). Fix writes:
//   (a) q-interleave qrel=(pl>>2)+(pl&3)*16 (decorrelates q&1 from lane),
//   (b) j-rotation j=(i+pl)&3 (pos&3 varies within inst).
//   Same bytes -> same slots: numerics bit-identical to R8/R11.
//   Prep fused: A-frags computed inline from P (bit-identical f2bf),
//   single kernel launch, afr/workspace eliminated.

constexpr int D    = 16;
constexpr int L    = 1000000;
constexpr int W    = 64;
constexpr int K    = 8;
constexpr int PADL = 31;
constexpr int NMID = L - W + 1;          // 999937
constexpr int TPB  = 256;                // 4 waves
constexpr int OTW  = 8;                  // out 32-pos tiles per wave
constexpr int CTW  = OTW + 2;            // computed tiles per wave
constexpr int BLK_OUT = 4 * OTW * 32;    // 1024 positions per block
constexpr int XS   = 1104;               // staged positions (need 1103), 276 quads
constexpr int NQ   = XS / 4;             // 276 float4 quads per row
constexpr int SIT  = (NQ + 63) / 64;     // 5 staging iterations
constexpr int NBLK = (NMID + BLK_OUT - 1) / BLK_OUT;   // 977
constexpr int NGRID = NBLK + K;          // +8 edge blocks

typedef __attribute__((ext_vector_type(8)))  short short8;
typedef __attribute__((ext_vector_type(16))) float floatx16;

__device__ __forceinline__ unsigned short f2bf(float f) {
    union { float f; unsigned u; } v; v.f = f;
    unsigned u = v.u + 0x7fff + ((v.u >> 16) & 1);   // RNE
    return (unsigned short)(u >> 16);
}

__device__ __forceinline__ unsigned long long pack4(float a, float b,
                                                    float c, float d) {
    return (unsigned long long)f2bf(a)
         | ((unsigned long long)f2bf(b) << 16)
         | ((unsigned long long)f2bf(c) << 32)
         | ((unsigned long long)f2bf(d) << 48);
}

__device__ __forceinline__ float selx(const float4 v, int j) {
    return j == 0 ? v.x : j == 1 ? v.y : j == 2 ? v.z : v.w;
}

__global__ __launch_bounds__(TPB, 3) void fullscan_mid(
    const float* __restrict__ x, const float* __restrict__ P,
    float* __restrict__ out)
{
    __shared__ __align__(16) unsigned short xs[XS * 16];   // 35328 B
    const int bid = blockIdx.x;
    const int tid = threadIdx.x;

    if (bid >= NBLK) {
        // Edge block: k = bid - NBLK, 63 outputs (fp32 exact).
        const int k = bid - NBLK;
        const int j = tid;
        if (j < PADL) {
            float acc = 0.0f;
            for (int m = 0; m <= 32 + j; ++m)
#pragma unroll
                for (int d = 0; d < D; ++d)
                    acc = fmaf(x[d * L + m], P[(k * D + d) * W + m], acc);
            out[k * L + j] = acc;
        } else if (j < 2 * PADL + 1) {
            const int jj = j - PADL;                  // 0..31
            float acc = 0.0f;
            for (int m = jj + 1; m < W; ++m)
#pragma unroll
                for (int d = 0; d < D; ++d)
                    acc = fmaf(x[d * L + (L - W) + m], P[(k * D + d) * W + m], acc);
            out[k * L + PADL + NMID + jj] = acc;
        }
        return;
    }

    const int s0   = bid * BLK_OUT;
    const int lane = tid & 63;
    const int wv   = tid >> 6;

    // Stage x: thread (pl, dq) owns 4 d-rows; float4 over position-quads.
    // Layout (R8, read-verified 2-way-free): 8B word (pos, dq) at shorts
    // pos*16 + ((dq*4) ^ (((pos>>2)&1)*8)).
    // Write-conflict fix: q-interleave (qrel=(pl>>2)+(pl&3)*16) + j-rotation
    // (j=(i+pl)&3): per write inst, starts cover all 8 16B slots / 8 lanes.
    {
        const int pl = tid & 63;
        const int dq = tid >> 6;            // d-quad 0..3 (fixed per wave)
        const int qrel = (pl >> 2) + (pl & 3) * 16;   // 0..63 interleaved
        if (s0 + XS <= L) {
            const float4* xq0 = (const float4*)(x + (4 * dq + 0) * L + s0);
            const float4* xq1 = (const float4*)(x + (4 * dq + 1) * L + s0);
            const float4* xq2 = (const float4*)(x + (4 * dq + 2) * L + s0);
            const float4* xq3 = (const float4*)(x + (4 * dq + 3) * L + s0);
#pragma unroll 2
            for (int it = 0; it < SIT; ++it) {
                const int q = it * 64 + qrel;
                if (q < NQ) {
                    const float4 v0 = xq0[q];
                    const float4 v1 = xq1[q];
                    const float4 v2 = xq2[q];
                    const float4 v3 = xq3[q];
                    const int swz = q & 1;            // (pos>>2)&1 for pos=4q+j
#pragma unroll
                    for (int i = 0; i < 4; ++i) {
                        const int j = (i + pl) & 3;   // rotate pos&3 across lanes
                        const int pos = 4 * q + j;
                        *(unsigned long long*)
                            &xs[pos * 16 + ((dq * 4) ^ (swz * 8))] =
                            pack4(selx(v0, j), selx(v1, j),
                                  selx(v2, j), selx(v3, j));
                    }
                }
            }
        } else {
            // Last mid block only: scalar path with bounds clamp (R8 layout).
            const float* xr0 = x + (4 * dq + 0) * L + s0;
            const float* xr1 = x + (4 * dq + 1) * L + s0;
            const float* xr2 = x + (4 * dq + 2) * L + s0;
            const float* xr3 = x + (4 * dq + 3) * L + s0;
#pragma unroll 1
            for (int b = 0; b < XS; b += 64) {
                const int pos = b + pl;
                if (pos < XS) {
                    const bool ok = (s0 + pos) < L;
                    const float v0 = ok ? xr0[pos] : 0.0f;
                    const float v1 = ok ? xr1[pos] : 0.0f;
                    const float v2 = ok ? xr2[pos] : 0.0f;
                    const float v3 = ok ? xr3[pos] : 0.0f;
                    const int swz = (pos >> 2) & 1;
                    *(unsigned long long*)&xs[pos * 16 + ((dq * 4) ^ (swz * 8))] =
                        pack4(v0, v1, v2, v3);
                }
            }
        }
    }

    // A fragments computed inline from P (prep kernel fused; bit-identical
    // f2bf of the same P values). P is 8KB -> L2-hot. Issued after staging
    // loads so latency hides under the barrier wait.
    short8 A[16];
    {
        const int m = lane & 31, hA = lane >> 5;
        const int k = m & 7, g = m >> 3;
        const float* Pb = P + ((k * D + 8 * hA) * W + 16 * g);
#pragma unroll
        for (int c = 0; c < 16; ++c)
#pragma unroll
            for (int j = 0; j < 8; ++j)
                A[c][j] = (short)f2bf(Pb[j * W + c]);
    }

    __syncthreads();

    const int n  = lane & 31;
    const int h  = lane >> 5;
    const int hb = h * 8;
    const int wbase = wv * OTW;             // first local out-tile of this wave

    // Incremental cross-tile combine state (16 regs):
    //   at iter jj, emit tile jj-2: v = pendA + shfl(g3);
    //   then pendA = pendB + acc[kk+8] + shfl(g1); save pendB/prev4/prev12.
    float pendA[4], pendB[4], prev4[4], prev12[4];

#pragma unroll
    for (int jj = 0; jj < CTW; ++jj) {
        floatx16 acc;
#pragma unroll
        for (int r = 0; r < 16; ++r) acc[r] = 0.0f;
        const int p0 = (wbase + jj) * 32 + n;

        // Group-4 double-buffered B reads (R8 swizzle: 2-way-free).
#define BRD(pos) (*(const short8*)&xs[(pos) * 16 + (hb ^ ((((pos) >> 2) & 1) * 8))])
        short8 Bc[4], Bn[4];
#pragma unroll
        for (int u = 0; u < 4; ++u) Bc[u] = BRD(p0 + u);
        // group 0: prefetch group 1, mfma chunks 0..3
#pragma unroll
        for (int u = 0; u < 4; ++u) Bn[u] = BRD(p0 + 4 + u);
#pragma unroll
        for (int u = 0; u < 4; ++u)
            acc = __builtin_amdgcn_mfma_f32_32x32x16_bf16(A[u], Bc[u], acc, 0, 0, 0);
        // group 1: prefetch group 2, mfma chunks 4..7
#pragma unroll
        for (int u = 0; u < 4; ++u) Bc[u] = BRD(p0 + 8 + u);
#pragma unroll
        for (int u = 0; u < 4; ++u)
            acc = __builtin_amdgcn_mfma_f32_32x32x16_bf16(A[4 + u], Bn[u], acc, 0, 0, 0);
        // group 2: prefetch group 3, mfma chunks 8..11
#pragma unroll
        for (int u = 0; u < 4; ++u) Bn[u] = BRD(p0 + 12 + u);
#pragma unroll
        for (int u = 0; u < 4; ++u)
            acc = __builtin_amdgcn_mfma_f32_32x32x16_bf16(A[8 + u], Bc[u], acc, 0, 0, 0);
        // group 3: mfma chunks 12..15
#pragma unroll
        for (int u = 0; u < 4; ++u)
            acc = __builtin_amdgcn_mfma_f32_32x32x16_bf16(A[12 + u], Bn[u], acc, 0, 0, 0);
#undef BRD

        if (jj >= 2) {
            const int ot = jj - 2;
            const int t = s0 + (wbase + ot) * 32 + n;
#pragma unroll
            for (int kk = 0; kk < 4; ++kk) {
                const float g3t = (n >= 16) ? prev12[kk] : acc[kk + 12];
                const float v = pendA[kk] + __shfl_xor(g3t, 16, 64);
                if (t < NMID)
                    out[(kk + 4 * h) * L + PADL + t] = v;
            }
        }
        if (jj >= 1) {
#pragma unroll
            for (int kk = 0; kk < 4; ++kk) {
                const float g1t = (n >= 16) ? prev4[kk] : acc[kk + 4];
                pendA[kk] = pendB[kk] + acc[kk + 8] + __shfl_xor(g1t, 16, 64);
            }
        }
#pragma unroll
        for (int kk = 0; kk < 4; ++kk) {
            pendB[kk]  = acc[kk];
            prev4[kk]  = acc[kk + 4];
            prev12[kk] = acc[kk + 12];
        }
    }
}

extern "C" void kernel_launch(void* const* d_in, const int* in_sizes, int n_in,
                              void* d_out, int out_size, void* d_ws, size_t ws_size,
                              hipStream_t stream)
{
    const float* x = (const float*)d_in[0];   // (D, L)
    const float* P = (const float*)d_in[1];   // (K, D, W)
    float* out = (float*)d_out;

    hipLaunchKernelGGL(fullscan_mid, dim3(NGRID), dim3(TPB), 0, stream,
                       x, P, out);
}

// Round 14
// 134.950 us; speedup vs baseline: 1.1800x; 1.0235x over previous
//
#include <hip/hip_runtime.h>

// FullScan via bf16 MFMA 32x32x16, full-M packing.
// out[k,t] = sum_{d<16,w<64} x[d,t+w]*P[k,d,w], K=8, L=1e6.
// M=32 rows = (k, tap-group g): row m = k + 8g (g covers taps [16g,16g+16)).
//   D_g[k](s) = sum_{c<16,d} P[k,d,16g+c] x[d,s+c]
//   out[k,t]  = sum_g D_g[k](t + 16g)
// C/D: col=lane&31, row=(reg&3)+8*(reg>>2)+4h => reg kk+4g = D_g[kk+4h](n).
// R18: single variable vs R11 (proven 55.1us): ROLL the tile loop
//      (#pragma unroll 1 on jj). Theory: instruction-fetch bound.
//      Audit: no data pipe >32% of the 132k-cy wall; wave lifetime 47k cy
//      vs 5k cy pipe work; invariant across ALL 10 null experiments =
//      the ~25-30KB fully-unrolled compute body. I-fetch arithmetic:
//      ~40KB I-bytes/wave-pass x 12 waves at different offsets ~ 15k
//      cy/generation x 3.85 = ~58k cy — the unexplained stall.
//      Rolled body ~1.4KB: all waves loop the same hot lines.
//      All inner indexing static (A[c], Bc/Bn, pend arrays) — reg-safe.
//      Staging/swizzle/epilogue/prep = R11 verbatim.

constexpr int D    = 16;
constexpr int L    = 1000000;
constexpr int W    = 64;
constexpr int K    = 8;
constexpr int PADL = 31;
constexpr int NMID = L - W + 1;          // 999937
constexpr int TPB  = 256;                // 4 waves
constexpr int OTW  = 8;                  // out 32-pos tiles per wave
constexpr int CTW  = OTW + 2;            // computed tiles per wave
constexpr int BLK_OUT = 4 * OTW * 32;    // 1024 positions per block
constexpr int XS   = 1104;               // staged positions (need 1103), 276 quads
constexpr int NQ   = XS / 4;             // 276 float4 quads per row
constexpr int NBLK = (NMID + BLK_OUT - 1) / BLK_OUT;   // 977
constexpr int NGRID = NBLK + K;          // +8 edge blocks

typedef __attribute__((ext_vector_type(8)))  short short8;
typedef __attribute__((ext_vector_type(16))) float floatx16;

__device__ __forceinline__ unsigned short f2bf(float f) {
    union { float f; unsigned u; } v; v.f = f;
    unsigned u = v.u + 0x7fff + ((v.u >> 16) & 1);   // RNE
    return (unsigned short)(u >> 16);
}

__device__ __forceinline__ unsigned long long pack4(float a, float b,
                                                    float c, float d) {
    return (unsigned long long)f2bf(a)
         | ((unsigned long long)f2bf(b) << 16)
         | ((unsigned long long)f2bf(c) << 32)
         | ((unsigned long long)f2bf(d) << 48);
}

__global__ __launch_bounds__(TPB, 3) void fullscan_mid(
    const float* __restrict__ x, const float* __restrict__ P,
    const unsigned short* __restrict__ afr, float* __restrict__ out)
{
    __shared__ __align__(16) unsigned short xs[XS * 16];   // 35328 B
    const int bid = blockIdx.x;
    const int tid = threadIdx.x;

    if (bid >= NBLK) {
        // Edge block: k = bid - NBLK, 63 outputs (fp32 exact).
        const int k = bid - NBLK;
        const int j = tid;
        if (j < PADL) {
            float acc = 0.0f;
            for (int m = 0; m <= 32 + j; ++m)
#pragma unroll
                for (int d = 0; d < D; ++d)
                    acc = fmaf(x[d * L + m], P[(k * D + d) * W + m], acc);
            out[k * L + j] = acc;
        } else if (j < 2 * PADL + 1) {
            const int jj = j - PADL;                  // 0..31
            float acc = 0.0f;
            for (int m = jj + 1; m < W; ++m)
#pragma unroll
                for (int d = 0; d < D; ++d)
                    acc = fmaf(x[d * L + (L - W) + m], P[(k * D + d) * W + m], acc);
            out[k * L + PADL + NMID + jj] = acc;
        }
        return;
    }

    const int s0   = bid * BLK_OUT;
    const int lane = tid & 63;
    const int wv   = tid >> 6;

    // Stage x: thread (pl, dq) owns 4 d-rows; float4 over position-quads.
    // Column-XOR swizzle: 16B unit for (pos=4q+j, half) stored at slot
    // (j ^ (q&3)) within the 128B row q -> write banks spread 4x.
    {
        const int pl = tid & 63;
        const int dq = tid >> 6;            // d-quad 0..3
        if (s0 + XS <= L) {
            const float4* xq0 = (const float4*)(x + (4 * dq + 0) * L + s0);
            const float4* xq1 = (const float4*)(x + (4 * dq + 1) * L + s0);
            const float4* xq2 = (const float4*)(x + (4 * dq + 2) * L + s0);
            const float4* xq3 = (const float4*)(x + (4 * dq + 3) * L + s0);
#pragma unroll 2
            for (int it = 0; it < 5; ++it) {
                const int q = it * 64 + pl;
                if (q < NQ) {
                    const float4 v0 = xq0[q];
                    const float4 v1 = xq1[q];
                    const float4 v2 = xq2[q];
                    const float4 v3 = xq3[q];
                    const int rot = q & 3;
                    unsigned short* base = &xs[q * 64 + dq * 4];
                    *(unsigned long long*)(base + (0 ^ rot) * 16) = pack4(v0.x, v1.x, v2.x, v3.x);
                    *(unsigned long long*)(base + (1 ^ rot) * 16) = pack4(v0.y, v1.y, v2.y, v3.y);
                    *(unsigned long long*)(base + (2 ^ rot) * 16) = pack4(v0.z, v1.z, v2.z, v3.z);
                    *(unsigned long long*)(base + (3 ^ rot) * 16) = pack4(v0.w, v1.w, v2.w, v3.w);
                }
            }
        } else {
            // Last mid block only: scalar path with bounds clamp.
            const float* xr0 = x + (4 * dq + 0) * L + s0;
            const float* xr1 = x + (4 * dq + 1) * L + s0;
            const float* xr2 = x + (4 * dq + 2) * L + s0;
            const float* xr3 = x + (4 * dq + 3) * L + s0;
#pragma unroll 1
            for (int b = 0; b < XS; b += 64) {
                const int pos = b + pl;
                if (pos < XS) {
                    const bool ok = (s0 + pos) < L;
                    const float v0 = ok ? xr0[pos] : 0.0f;
                    const float v1 = ok ? xr1[pos] : 0.0f;
                    const float v2 = ok ? xr2[pos] : 0.0f;
                    const float v3 = ok ? xr3[pos] : 0.0f;
                    const int idx = (pos * 16 + dq * 4) ^ (((pos >> 2) & 3) << 4);
                    *(unsigned long long*)&xs[idx] = pack4(v0, v1, v2, v3);
                }
            }
        }
    }

    // Resident A fragments loaded AFTER staging: latency hides under the
    // barrier wait for other waves; keeps staging-phase reg pressure low.
    short8 A[16];
#pragma unroll
    for (int c = 0; c < 16; ++c)
        A[c] = *(const short8*)(afr + (c * 64 + lane) * 8);

    __syncthreads();

    const int n  = lane & 31;
    const int h  = lane >> 5;
    const int hb = h * 8;
    const int wbase = wv * OTW;             // first local out-tile of this wave

    // Incremental cross-tile combine state (16 regs):
    //   at iter jj, emit tile jj-2: v = pendA + shfl(g3);
    //   then pendA = pendB + acc[kk+8] + shfl(g1); save pendB/prev4/prev12.
    float pendA[4], pendB[4], prev4[4], prev12[4];

    // ROLLED tile loop: one ~1.4KB body, 10 dynamic iterations.
#pragma unroll 1
    for (int jj = 0; jj < CTW; ++jj) {
        floatx16 acc;
#pragma unroll
        for (int r = 0; r < 16; ++r) acc[r] = 0.0f;
        const int p0 = (wbase + jj) * 32 + n;

        // Group-4 double-buffered B reads: 4 ds_read_b128 issued per group,
        // consumed one full group later.
#define BRD(pos) (*(const short8*)&xs[((pos) * 16 + hb) ^ ((((pos) >> 2) & 3) << 4)])
        short8 Bc[4], Bn[4];
#pragma unroll
        for (int u = 0; u < 4; ++u) Bc[u] = BRD(p0 + u);
        // group 0: prefetch group 1, mfma chunks 0..3
#pragma unroll
        for (int u = 0; u < 4; ++u) Bn[u] = BRD(p0 + 4 + u);
#pragma unroll
        for (int u = 0; u < 4; ++u)
            acc = __builtin_amdgcn_mfma_f32_32x32x16_bf16(A[u], Bc[u], acc, 0, 0, 0);
        // group 1: prefetch group 2, mfma chunks 4..7
#pragma unroll
        for (int u = 0; u < 4; ++u) Bc[u] = BRD(p0 + 8 + u);
#pragma unroll
        for (int u = 0; u < 4; ++u)
            acc = __builtin_amdgcn_mfma_f32_32x32x16_bf16(A[4 + u], Bn[u], acc, 0, 0, 0);
        // group 2: prefetch group 3, mfma chunks 8..11
#pragma unroll
        for (int u = 0; u < 4; ++u) Bn[u] = BRD(p0 + 12 + u);
#pragma unroll
        for (int u = 0; u < 4; ++u)
            acc = __builtin_amdgcn_mfma_f32_32x32x16_bf16(A[8 + u], Bc[u], acc, 0, 0, 0);
        // group 3: mfma chunks 12..15
#pragma unroll
        for (int u = 0; u < 4; ++u)
            acc = __builtin_amdgcn_mfma_f32_32x32x16_bf16(A[12 + u], Bn[u], acc, 0, 0, 0);
#undef BRD

        if (jj >= 2) {
            const int ot = jj - 2;
            const int t = s0 + (wbase + ot) * 32 + n;
#pragma unroll
            for (int kk = 0; kk < 4; ++kk) {
                const float g3t = (n >= 16) ? prev12[kk] : acc[kk + 12];
                const float v = pendA[kk] + __shfl_xor(g3t, 16, 64);
                if (t < NMID)
                    out[(kk + 4 * h) * L + PADL + t] = v;
            }
        }
        if (jj >= 1) {
#pragma unroll
            for (int kk = 0; kk < 4; ++kk) {
                const float g1t = (n >= 16) ? prev4[kk] : acc[kk + 4];
                pendA[kk] = pendB[kk] + acc[kk + 8] + __shfl_xor(g1t, 16, 64);
            }
        }
#pragma unroll
        for (int kk = 0; kk < 4; ++kk) {
            pendB[kk]  = acc[kk];
            prev4[kk]  = acc[kk + 4];
            prev12[kk] = acc[kk + 12];
        }
    }
}

// Prep: A-fragment table. afr[c][lane][j] = bf16(P[k, d, w]),
// m=lane&31, h=lane>>5, k=m&7, g=m>>3, d=8h+j, w=16g+c.
__global__ void fullscan_prep(const float* __restrict__ P,
                              unsigned short* __restrict__ afr)
{
    const int u = blockIdx.x * 256 + threadIdx.x;   // 32 blocks x 256 = 8192
    const int c = u >> 9, lane = (u >> 3) & 63, j = u & 7;
    const int m = lane & 31, h = lane >> 5;
    const int k = m & 7, g = m >> 3;
    const int d = 8 * h + j;
    const int w = 16 * g + c;
    afr[u] = f2bf(P[(k * D + d) * W + w]);
}

extern "C" void kernel_launch(void* const* d_in, const int* in_sizes, int n_in,
                              void* d_out, int out_size, void* d_ws, size_t ws_size,
                              hipStream_t stream)
{
    const float* x = (const float*)d_in[0];   // (D, L)
    const float* P = (const float*)d_in[1];   // (K, D, W)
    float* out = (float*)d_out;
    unsigned short* afr = (unsigned short*)d_ws;   // 16 KB

    hipLaunchKernelGGL(fullscan_prep, dim3(32), dim3(256), 0, stream, P, afr);
    hipLaunchKernelGGL(fullscan_mid, dim3(NGRID), dim3(TPB), 0, stream,
                       x, P, afr, out);
}